// Round 2
// 2610.998 us; speedup vs baseline: 1.0134x; 1.0134x over previous
//
#include <hip/hip_runtime.h>
#include <hip/hip_cooperative_groups.h>

namespace cg = cooperative_groups;

// WaveNet fused implementation, fp32.
// Layout trick: with dilation fixed at 1024, t = r + 1024*s decomposes the field
// into 8192 independent chains (b, r) of 16 steps x 32 channels.
// ws layout (floats): h [8192][32][16] @0, skip same @4M, stats @8M.
// Layer z-stats (8-way slot-replicated) live at the head of d_out (dead until k_ep_c).

#define EPSV 1e-5f
#define RN   (1.f/131072.f)

#define H_OFF  0
#define SK_OFF (4*1024*1024)
#define ST_OFF (8*1024*1024)
#define ST_SKIP 2560   // skip sum[32], sumsq[32]
#define ST_MU   2624   // y1 mean-sum [32]
#define ST_Y    2656   // y1 second-moment sums [32][32]
#define ST_A2   3680   // bn2 scale [256]
#define ST_B2   3936   // bn2 shift [256]
#define ST_TOT  4192
#define LST_N   (40*8*64)   // layer z-stats: [L][slot][sum32|sumsq32]

__device__ __forceinline__ float rcp_f(float x) { return __builtin_amdgcn_rcpf(x); }
__device__ __forceinline__ float tanh_f(float x) {
    float e = __expf(2.f * x);                 // inf for big x -> 1; 0 for very neg -> -1
    return 1.f - 2.f * rcp_f(e + 1.f);
}
__device__ __forceinline__ float sigm_f(float x) { return rcp_f(1.f + __expf(-x)); }
__device__ __forceinline__ float mish_f(float x) {
    float e = __expf(x);
    float sp = (x > 15.f) ? x : __logf(1.f + e);   // softplus, stable both tails
    return x * tanh_f(sp);
}

// ---------------- zero a region (ws / d_out are poisoned every launch) --------
__global__ void k_zero(float* __restrict__ p, int n) {
    int i = blockIdx.x * 256 + threadIdx.x;
    if (i < n) p[i] = 0.f;
}

// ---------------- start conv: h = W_s @ shift_right(x,1) + b_s ; skip = 0 -----
// block = 256 thr = 16 r' x 16 s positions; 512 blocks (b in blk>>6, r0=(blk&63)*16)
__global__ __launch_bounds__(256) void k_start(
        const float* __restrict__ x, const float* __restrict__ sw_g,
        const float* __restrict__ sb_g, float* __restrict__ h, float* __restrict__ skip)
{
    __shared__ float sw[256*36];   // W [c][o], row stride 36 (pad: bank rotate + 16B align)
    __shared__ float sb[32];
    int tid = threadIdx.x, blk = blockIdx.x;
    int b = blk >> 6, r0 = (blk & 63) << 4;
    for (int k = tid; k < 8192; k += 256) {        // sw_g is [o][c], k = o*256+c
        int o = k >> 8, c = k & 255;
        sw[c*36 + o] = sw_g[k];
    }
    if (tid < 32) sb[tid] = sb_g[tid];
    __syncthreads();

    int rr = tid & 15, s = tid >> 4;
    int t = r0 + rr + (s << 10);
    bool valid = (t >= 1);
    const float* xr = x + (long)b*256*16384 + (valid ? (t-1) : 0);
    float acc[32];
    #pragma unroll
    for (int o = 0; o < 32; ++o) acc[o] = 0.f;
    for (int c = 0; c < 256; ++c) {
        float xv = xr[(long)c*16384];
        xv = valid ? xv : 0.f;
        const float4* wrow = (const float4*)&sw[c*36];
        #pragma unroll
        for (int o4 = 0; o4 < 8; ++o4) {
            float4 w = wrow[o4];
            acc[o4*4+0] += w.x*xv; acc[o4*4+1] += w.y*xv;
            acc[o4*4+2] += w.z*xv; acc[o4*4+3] += w.w*xv;
        }
    }
    __syncthreads();                               // done reading sw; reuse as h stage
    #pragma unroll
    for (int o = 0; o < 32; ++o) sw[(rr*32 + o)*16 + s] = acc[o] + sb[o];
    __syncthreads();
    float4* hd = (float4*)(h + (long)blk*8192);
    float4* sd = (float4*)(skip + (long)blk*8192);
    const float4* ss = (const float4*)sw;
    float4 z4 = make_float4(0.f, 0.f, 0.f, 0.f);
    for (int k = tid; k < 2048; k += 256) { hd[k] = ss[k]; sd[k] = z4; }
}

// ---------------- fused 40-layer kernel (cooperative) -------------------------
// 512 blocks x 512 thr; each thread owns chain chl (16/block), channel o, 16 steps.
// h / skip / z stay in VGPRs across all 40 layers; the only cross-block dependency
// per layer is the z BN statistic: slot-replicated atomics + grid.sync(), read
// back with agent-scope coherent loads (lanes 0..31 only) and LDS-broadcast.
// LDS = 16384(s_w) + 4096(s_r) + 32768(s_hg) + 2048(s_red) + 256(s_ab) = 55552 B
// -> 2 blocks/CU (111 KB of 160 KB: 53 KB slack, safe vs alloc granularity).
// __launch_bounds__(512,4): 16 waves/CU = 2 blocks/CU, VGPR cap 128.
__global__ __launch_bounds__(512, 4) void k_fused(
        const float* __restrict__ gt_w, const float* __restrict__ gt_b,
        const float* __restrict__ gs_w, const float* __restrict__ gs_b,
        const float* __restrict__ res_w, const float* __restrict__ res_b,
        const float* __restrict__ bn_g, const float* __restrict__ bn_b,
        const float* __restrict__ h, float* __restrict__ skip,
        float* __restrict__ st, float* __restrict__ lst)
{
    __shared__ float s_w[4096];      // [i][o][4] = {wt0, wt1, ws0, ws1}
    __shared__ float s_r[1024];      // [i][o]
    __shared__ float s_hg[8192];     // per-chain h then g, [chl][c][16], 16 chains
    __shared__ float s_red[8][32][2];
    __shared__ float s_ab[64];       // bn affine broadcast: a[32], b[32]

    int tid = threadIdx.x;
    int o = tid & 31, chl = tid >> 5;          // chl in [0,16)
    long base = (long)blockIdx.x*8192 + chl*512 + o*16;
    int slot = blockIdx.x & 7;

    float hreg[16], sk[16], zr[16];
    {
        const float4* hp4 = (const float4*)(h + base);
        #pragma unroll
        for (int q = 0; q < 4; ++q) {
            float4 t4 = hp4[q];
            hreg[4*q+0]=t4.x; hreg[4*q+1]=t4.y; hreg[4*q+2]=t4.z; hreg[4*q+3]=t4.w;
        }
    }
    #pragma unroll
    for (int s = 0; s < 16; ++s) sk[s] = 0.f;

    cg::grid_group grid = cg::this_grid();

    for (int L = 0; L < 40; ++L) {
        // stage weights: gt_w/gs_w are [L][o][i][2], res_w is [L][o][i]
        for (int k = tid; k < 1024; k += 512) {
            int oo = k >> 5, ii = k & 31;
            float2 a = ((const float2*)(gt_w + (long)L*2048))[k];
            float2 c = ((const float2*)(gs_w + (long)L*2048))[k];
            float* d = &s_w[(ii*32 + oo)*4];
            d[0] = a.x; d[1] = a.y; d[2] = c.x; d[3] = c.y;
            s_r[ii*32 + oo] = res_w[(long)L*1024 + k];
        }

        // apply previous layer's bn residual: h += a*z + b  (stats synced last iter)
        if (L > 0) {
            if (tid < 32) {
                float ssum = 0.f, ssq = 0.f;
                #pragma unroll
                for (int r = 0; r < 8; ++r) {
                    ssum += __hip_atomic_load(&lst[((L-1)*8 + r)*64 + tid],
                                              __ATOMIC_RELAXED, __HIP_MEMORY_SCOPE_AGENT);
                    ssq  += __hip_atomic_load(&lst[((L-1)*8 + r)*64 + 32 + tid],
                                              __ATOMIC_RELAXED, __HIP_MEMORY_SCOPE_AGENT);
                }
                float m = ssum * RN;
                float v = ssq * RN - m*m;
                float a = rsqrtf(v + EPSV) * bn_g[(L-1)*32 + tid];
                s_ab[tid] = a;
                s_ab[32 + tid] = bn_b[(L-1)*32 + tid] - m*a;
            }
            __syncthreads();
            float a = s_ab[o], bb = s_ab[32 + o];
            #pragma unroll
            for (int s = 0; s < 16; ++s) hreg[s] += zr[s]*a + bb;
        }

        // stage h for cross-channel broadcast (own chain only reads it)
        float4* hs4 = (float4*)&s_hg[chl*512 + o*16];
        #pragma unroll
        for (int q = 0; q < 4; ++q)
            hs4[q] = make_float4(hreg[4*q], hreg[4*q+1], hreg[4*q+2], hreg[4*q+3]);
        __syncthreads();   // weights + h staged

        // gate matvecs: aT/aS[s] = b + sum_i (w1*h[i][s] + w0*h[i][s-1])
        float aT[16], aS[16];
        float gtb = gt_b[L*32 + o], gsb = gs_b[L*32 + o];
        #pragma unroll
        for (int s = 0; s < 16; ++s) { aT[s] = gtb; aS[s] = gsb; }
        #pragma unroll 4
        for (int i = 0; i < 32; ++i) {
            float4 w = *(const float4*)&s_w[(i*32 + o)*4];
            const float4* hr = (const float4*)&s_hg[chl*512 + i*16];
            float hp = 0.f;                               // s=0 shifted tap is zero-pad
            #pragma unroll
            for (int s4 = 0; s4 < 4; ++s4) {
                float4 hv = hr[s4];
                int s = 4*s4;
                aT[s+0] += w.y*hv.x + w.x*hp;   aS[s+0] += w.w*hv.x + w.z*hp;
                aT[s+1] += w.y*hv.y + w.x*hv.x; aS[s+1] += w.w*hv.y + w.z*hv.x;
                aT[s+2] += w.y*hv.z + w.x*hv.y; aS[s+2] += w.w*hv.z + w.z*hv.y;
                aT[s+3] += w.y*hv.w + w.x*hv.z; aS[s+3] += w.w*hv.w + w.z*hv.z;
                hp = hv.w;
            }
        }
        float g[16];
        #pragma unroll
        for (int s = 0; s < 16; ++s) {
            g[s] = tanh_f(aT[s]) * sigm_f(aS[s]);
            sk[s] += g[s];
        }

        if (L < 39) {     // layer 39's z / bn stats are dead
            // restage g over h
            __syncthreads();
            #pragma unroll
            for (int q = 0; q < 4; ++q)
                hs4[q] = make_float4(g[4*q], g[4*q+1], g[4*q+2], g[4*q+3]);
            __syncthreads();

            // z = R @ g + rb  (kept in registers for next layer's bn residual)
            float rbv = res_b[L*32 + o];
            #pragma unroll
            for (int s = 0; s < 16; ++s) zr[s] = rbv;
            #pragma unroll 4
            for (int i = 0; i < 32; ++i) {
                float w = s_r[i*32 + o];
                const float4* gr = (const float4*)&s_hg[chl*512 + i*16];
                #pragma unroll
                for (int s4 = 0; s4 < 4; ++s4) {
                    float4 gv = gr[s4];
                    zr[4*s4+0] += w*gv.x; zr[4*s4+1] += w*gv.y;
                    zr[4*s4+2] += w*gv.z; zr[4*s4+3] += w*gv.w;
                }
            }

            // z stats: per-chain partial -> half-wave merge -> block LDS -> atomics
            float ps = 0.f, pq = 0.f;
            #pragma unroll
            for (int s = 0; s < 16; ++s) { ps += zr[s]; pq += zr[s]*zr[s]; }
            ps += __shfl_down(ps, 32); pq += __shfl_down(pq, 32);
            int wv = tid >> 6;
            if ((tid & 63) < 32) { s_red[wv][o][0] = ps; s_red[wv][o][1] = pq; }
            __syncthreads();
            if (tid < 32) {
                float a = 0.f;
                #pragma unroll
                for (int w8 = 0; w8 < 8; ++w8) a += s_red[w8][tid][0];
                atomicAdd(&lst[(L*8 + slot)*64 + tid], a);
            } else if (tid < 64) {
                int c = tid - 32;
                float a = 0.f;
                #pragma unroll
                for (int w8 = 0; w8 < 8; ++w8) a += s_red[w8][c][1];
                atomicAdd(&lst[(L*8 + slot)*64 + 32 + c], a);
            }
            grid.sync();   // stats of layer L complete + visible before layer L+1
        }
    }

    // final skip write + fold skip-stat pass (values still in regs)
    {
        float4* skp4 = (float4*)(skip + base);
        #pragma unroll
        for (int q = 0; q < 4; ++q)
            skp4[q] = make_float4(sk[4*q], sk[4*q+1], sk[4*q+2], sk[4*q+3]);

        float p2 = 0.f, q2 = 0.f;
        #pragma unroll
        for (int s = 0; s < 16; ++s) { p2 += sk[s]; q2 += sk[s]*sk[s]; }
        p2 += __shfl_down(p2, 32); q2 += __shfl_down(q2, 32);
        int wv = tid >> 6;
        __syncthreads();
        if ((tid & 63) < 32) { s_red[wv][o][0] = p2; s_red[wv][o][1] = q2; }
        __syncthreads();
        if (tid < 32) {
            float a = 0.f;
            #pragma unroll
            for (int w8 = 0; w8 < 8; ++w8) a += s_red[w8][tid][0];
            atomicAdd(&st[ST_SKIP + tid], a);
        } else if (tid < 64) {
            int c = tid - 32;
            float a = 0.f;
            #pragma unroll
            for (int w8 = 0; w8 < 8; ++w8) a += s_red[w8][c][1];
            atomicAdd(&st[ST_SKIP + 32 + c], a);
        }
    }
}

// ---------------- legacy per-layer kernel (fallback if coop launch refused) ---
__global__ __launch_bounds__(256) void k_layer(
        const float* __restrict__ gt_w, const float* __restrict__ gt_b,
        const float* __restrict__ gs_w, const float* __restrict__ gs_b,
        const float* __restrict__ res_w, const float* __restrict__ res_b,
        const float* __restrict__ bn_g, const float* __restrict__ bn_b,
        float* __restrict__ h, float* __restrict__ z, float* __restrict__ skip,
        float* __restrict__ st, int L)
{
    __shared__ float s_w[4096];
    __shared__ float s_r[1024];
    __shared__ float s_hg[4096];
    __shared__ float s_red[4][32][2];

    int tid = threadIdx.x;
    int o = tid & 31, chl = tid >> 5;
    long base = (long)blockIdx.x*4096 + chl*512 + o*16;

    for (int k = tid; k < 1024; k += 256) {
        int oo = k >> 5, ii = k & 31;
        float2 a = ((const float2*)(gt_w + (long)L*2048))[k];
        float2 c = ((const float2*)(gs_w + (long)L*2048))[k];
        float* d = &s_w[(ii*32 + oo)*4];
        d[0] = a.x; d[1] = a.y; d[2] = c.x; d[3] = c.y;
        s_r[ii*32 + oo] = res_w[(long)L*1024 + k];
    }

    float hreg[16];
    float4* hp4 = (float4*)(h + base);
    #pragma unroll
    for (int q = 0; q < 4; ++q) {
        float4 t4 = hp4[q];
        hreg[4*q+0]=t4.x; hreg[4*q+1]=t4.y; hreg[4*q+2]=t4.z; hreg[4*q+3]=t4.w;
    }
    if (L > 0) {
        float ssum = st[(L-1)*64 + o], ssq = st[(L-1)*64 + 32 + o];
        float m = ssum * RN;
        float v = ssq * RN - m*m;
        float a = rsqrtf(v + EPSV) * bn_g[(L-1)*32 + o];
        float bb = bn_b[(L-1)*32 + o] - m*a;
        const float4* zp4 = (const float4*)(z + base);
        #pragma unroll
        for (int q = 0; q < 4; ++q) {
            float4 t4 = zp4[q];
            hreg[4*q+0] += t4.x*a + bb; hreg[4*q+1] += t4.y*a + bb;
            hreg[4*q+2] += t4.z*a + bb; hreg[4*q+3] += t4.w*a + bb;
        }
        #pragma unroll
        for (int q = 0; q < 4; ++q)
            hp4[q] = make_float4(hreg[4*q], hreg[4*q+1], hreg[4*q+2], hreg[4*q+3]);
    }
    float4* hs4 = (float4*)&s_hg[chl*512 + o*16];
    #pragma unroll
    for (int q = 0; q < 4; ++q)
        hs4[q] = make_float4(hreg[4*q], hreg[4*q+1], hreg[4*q+2], hreg[4*q+3]);
    __syncthreads();

    float aT[16], aS[16];
    float gtb = gt_b[L*32 + o], gsb = gs_b[L*32 + o];
    #pragma unroll
    for (int s = 0; s < 16; ++s) { aT[s] = gtb; aS[s] = gsb; }
    #pragma unroll 4
    for (int i = 0; i < 32; ++i) {
        float4 w = *(const float4*)&s_w[(i*32 + o)*4];
        const float4* hr = (const float4*)&s_hg[chl*512 + i*16];
        float hp = 0.f;
        #pragma unroll
        for (int s4 = 0; s4 < 4; ++s4) {
            float4 hv = hr[s4];
            int s = 4*s4;
            aT[s+0] += w.y*hv.x + w.x*hp;   aS[s+0] += w.w*hv.x + w.z*hp;
            aT[s+1] += w.y*hv.y + w.x*hv.x; aS[s+1] += w.w*hv.y + w.z*hv.x;
            aT[s+2] += w.y*hv.z + w.x*hv.y; aS[s+2] += w.w*hv.z + w.z*hv.y;
            aT[s+3] += w.y*hv.w + w.x*hv.z; aS[s+3] += w.w*hv.w + w.z*hv.z;
            hp = hv.w;
        }
    }
    float g[16], sk[16];
    #pragma unroll
    for (int s = 0; s < 16; ++s) g[s] = tanh_f(aT[s]) * sigm_f(aS[s]);

    float4* skp4 = (float4*)(skip + base);
    #pragma unroll
    for (int q = 0; q < 4; ++q) {
        float4 t4 = skp4[q];
        sk[4*q+0] = t4.x + g[4*q+0]; sk[4*q+1] = t4.y + g[4*q+1];
        sk[4*q+2] = t4.z + g[4*q+2]; sk[4*q+3] = t4.w + g[4*q+3];
        skp4[q] = make_float4(sk[4*q], sk[4*q+1], sk[4*q+2], sk[4*q+3]);
    }

    __syncthreads();
    #pragma unroll
    for (int q = 0; q < 4; ++q)
        hs4[q] = make_float4(g[4*q], g[4*q+1], g[4*q+2], g[4*q+3]);
    __syncthreads();

    float az[16];
    float rbv = res_b[L*32 + o];
    #pragma unroll
    for (int s = 0; s < 16; ++s) az[s] = rbv;
    #pragma unroll 4
    for (int i = 0; i < 32; ++i) {
        float w = s_r[i*32 + o];
        const float4* gr = (const float4*)&s_hg[chl*512 + i*16];
        #pragma unroll
        for (int s4 = 0; s4 < 4; ++s4) {
            float4 gv = gr[s4];
            az[4*s4+0] += w*gv.x; az[4*s4+1] += w*gv.y;
            az[4*s4+2] += w*gv.z; az[4*s4+3] += w*gv.w;
        }
    }
    float4* zp4w = (float4*)(z + base);
    #pragma unroll
    for (int q = 0; q < 4; ++q)
        zp4w[q] = make_float4(az[4*q], az[4*q+1], az[4*q+2], az[4*q+3]);

    float ps = 0.f, pq = 0.f;
    #pragma unroll
    for (int s = 0; s < 16; ++s) { ps += az[s]; pq += az[s]*az[s]; }
    ps += __shfl_down(ps, 32); pq += __shfl_down(pq, 32);
    int wv = tid >> 6;
    if ((tid & 63) < 32) { s_red[wv][o][0] = ps; s_red[wv][o][1] = pq; }
    __syncthreads();
    if (tid < 32) {
        float a = s_red[0][tid][0] + s_red[1][tid][0] + s_red[2][tid][0] + s_red[3][tid][0];
        atomicAdd(&st[L*64 + tid], a);
    } else if (tid < 64) {
        int c = tid - 32;
        float a = s_red[0][c][1] + s_red[1][c][1] + s_red[2][c][1] + s_red[3][c][1];
        atomicAdd(&st[L*64 + 32 + c], a);
    }

    if (L == 39) {
        float p2 = 0.f, q2 = 0.f;
        #pragma unroll
        for (int s = 0; s < 16; ++s) { p2 += sk[s]; q2 += sk[s]*sk[s]; }
        p2 += __shfl_down(p2, 32); q2 += __shfl_down(q2, 32);
        __syncthreads();
        if ((tid & 63) < 32) { s_red[wv][o][0] = p2; s_red[wv][o][1] = q2; }
        __syncthreads();
        if (tid < 32) {
            float a = s_red[0][tid][0] + s_red[1][tid][0] + s_red[2][tid][0] + s_red[3][tid][0];
            atomicAdd(&st[ST_SKIP + tid], a);
        } else if (tid < 64) {
            int c = tid - 32;
            float a = s_red[0][c][1] + s_red[1][c][1] + s_red[2][c][1] + s_red[3][c][1];
            atomicAdd(&st[ST_SKIP + 32 + c], a);
        }
    }
}

// ---------------- epilogue A: y1 = mish(bn1(skip)); accumulate mean + 2nd moments
__global__ __launch_bounds__(256) void k_ep_a(
        const float* __restrict__ skip, const float* __restrict__ bn1_g,
        const float* __restrict__ bn1_b, float* __restrict__ st)
{
    __shared__ float sy[256*33];     // y1 [p][i], stride 33
    __shared__ float sA[32], sB[32];
    int tid = threadIdx.x;
    long cb = (long)blockIdx.x * 8192;
    if (tid < 32) {
        float ssum = st[ST_SKIP + tid], ssq = st[ST_SKIP + 32 + tid];
        float m = ssum * RN, v = ssq * RN - m*m;
        float a = rsqrtf(v + EPSV) * bn1_g[tid];
        sA[tid] = a; sB[tid] = bn1_b[tid] - m*a;
    }
    __syncthreads();
    for (int k = tid; k < 8192; k += 256) {
        int i = k & 31, p = k >> 5;
        int rr = p & 15, s = p >> 4;
        float v = skip[cb + rr*512 + i*16 + s];
        sy[p*33 + i] = mish_f(v * sA[i] + sB[i]);
    }
    __syncthreads();
    if (tid < 32) {
        float mu = 0.f;
        for (int p = 0; p < 256; ++p) mu += sy[p*33 + tid];
        atomicAdd(&st[ST_MU + tid], mu);
    }
    int jj = tid & 31, i0 = tid >> 5;    // 8 x 32 -> 4 (i,j) pairs per thread
    float a0 = 0.f, a1 = 0.f, a2 = 0.f, a3 = 0.f;
    for (int p = 0; p < 256; ++p) {
        float yj = sy[p*33 + jj];
        a0 += yj * sy[p*33 + i0];
        a1 += yj * sy[p*33 + i0 + 8];
        a2 += yj * sy[p*33 + i0 + 16];
        a3 += yj * sy[p*33 + i0 + 24];
    }
    atomicAdd(&st[ST_Y + (i0     )*32 + jj], a0);
    atomicAdd(&st[ST_Y + (i0 +  8)*32 + jj], a1);
    atomicAdd(&st[ST_Y + (i0 + 16)*32 + jj], a2);
    atomicAdd(&st[ST_Y + (i0 + 24)*32 + jj], a3);
}

// ---------------- epilogue B: analytic bn2 stats: var(e1_w@y1) = w^T Cov(y1) w --
__global__ void k_ep_b(
        const float* __restrict__ e1_w, const float* __restrict__ e1_b,
        const float* __restrict__ bn2_g, const float* __restrict__ bn2_b,
        float* __restrict__ st)
{
    __shared__ float mu[32];
    int o = threadIdx.x;
    if (o < 32) mu[o] = st[ST_MU + o] * RN;
    __syncthreads();
    float w[32];
    const float4* wr = (const float4*)(e1_w + o*32);
    #pragma unroll
    for (int q = 0; q < 8; ++q) {
        float4 t4 = wr[q];
        w[4*q]=t4.x; w[4*q+1]=t4.y; w[4*q+2]=t4.z; w[4*q+3]=t4.w;
    }
    float m2 = e1_b[o];
    #pragma unroll
    for (int i = 0; i < 32; ++i) m2 += w[i]*mu[i];
    float var = 0.f;
    for (int i = 0; i < 32; ++i) {
        float wi = w[i], mi = mu[i];
        for (int j = 0; j < 32; ++j)
            var += wi * w[j] * (st[ST_Y + i*32 + j]*RN - mi*mu[j]);
    }
    float a2 = rsqrtf(var + EPSV) * bn2_g[o];
    st[ST_A2 + o] = a2;
    st[ST_B2 + o] = bn2_b[o] - m2*a2;
}

// ---------------- epilogue C: out = e2 @ mish(bn2(e1 @ mish(bn1(skip)))) + b ----
// block = 256 thr (thread = output/e-channel), tile = 16 chains; 4 subtiles of
// 32 pos per block, 1024 blocks. LDS trimmed to exactly 40960 B -> 4 blocks/CU.
__global__ __launch_bounds__(256, 4) void k_ep_c(
        const float* __restrict__ skip,
        const float* __restrict__ bn1_g, const float* __restrict__ bn1_b,
        const float* __restrict__ e1_w, const float* __restrict__ e1_b,
        const float* __restrict__ e2_w, const float* __restrict__ e2_b,
        const float* __restrict__ st, float* __restrict__ out)
{
    __shared__ float y1l[32*32];     // [i][q]
    __shared__ float y2l[256*36];    // [i][q], stride 36 (bank rotate, 16B aligned)
    int tid = threadIdx.x;
    int blk2 = blockIdx.x;
    int blk = blk2 >> 1, half = blk2 & 1;
    int b = blk >> 6, r0 = (blk & 63) << 4;
    long cb = (long)blk * 8192;
    float w1[32];
    {
        const float4* wr = (const float4*)(e1_w + tid*32);
        #pragma unroll
        for (int q = 0; q < 8; ++q) {
            float4 t4 = wr[q];
            w1[4*q]=t4.x; w1[4*q+1]=t4.y; w1[4*q+2]=t4.z; w1[4*q+3]=t4.w;
        }
    }
    float a2 = st[ST_A2 + tid], b2 = st[ST_B2 + tid];
    float eb1 = e1_b[tid];
    float eb2 = e2_b[tid];
    const float4* w2row = (const float4*)(e2_w + (long)tid * 256);

    for (int st8 = half*4; st8 < half*4 + 4; ++st8) {   // q = sl*16+rr, s = st8*2+sl
        for (int k = tid; k < 1024; k += 256) {  // phase A: y1 (32 i x 32 q)
            int i = k >> 5, q = k & 31;
            float ssum = st[ST_SKIP + i], ssq = st[ST_SKIP + 32 + i];
            float m = ssum * RN, vv = ssq * RN - m*m;
            float a1 = rsqrtf(vv + EPSV) * bn1_g[i];
            float b1 = bn1_b[i] - m*a1;
            int rr = q & 15, sl = q >> 4;
            float v = skip[cb + rr*512 + i*16 + st8*2 + sl];
            y1l[i*32 + q] = mish_f(v * a1 + b1);
        }
        __syncthreads();
        // phase B: z2 = e1@y1 (thread = channel), y2 = mish(bn2(z2)) -> LDS
        #pragma unroll 2
        for (int q4 = 0; q4 < 8; ++q4) {
            float4 acc = make_float4(eb1, eb1, eb1, eb1);
            #pragma unroll 8
            for (int i = 0; i < 32; ++i) {
                float4 yv = *(const float4*)&y1l[i*32 + q4*4];
                float wi = w1[i];
                acc.x += wi*yv.x; acc.y += wi*yv.y; acc.z += wi*yv.z; acc.w += wi*yv.w;
            }
            float4 y2v;
            y2v.x = mish_f(acc.x*a2 + b2);
            y2v.y = mish_f(acc.y*a2 + b2);
            y2v.z = mish_f(acc.z*a2 + b2);
            y2v.w = mish_f(acc.w*a2 + b2);
            *(float4*)&y2l[tid*36 + q4*4] = y2v;
        }
        __syncthreads();
        // phase C: out row = e2_w[tid,:] @ y2 (the big GEMM)
        float acc[32];
        #pragma unroll
        for (int q = 0; q < 32; ++q) acc[q] = eb2;
        for (int i4 = 0; i4 < 64; ++i4) {
            float4 w4 = w2row[i4];
            float wa[4] = {w4.x, w4.y, w4.z, w4.w};
            #pragma unroll
            for (int ii = 0; ii < 4; ++ii) {
                float wv = wa[ii];
                const float* yr = &y2l[(i4*4 + ii)*36];
                #pragma unroll
                for (int q4 = 0; q4 < 8; ++q4) {
                    float4 yv = *(const float4*)&yr[q4*4];
                    acc[q4*4+0] += wv*yv.x; acc[q4*4+1] += wv*yv.y;
                    acc[q4*4+2] += wv*yv.z; acc[q4*4+3] += wv*yv.w;
                }
            }
        }
        long ob = ((long)b*256 + tid)*16384 + (long)(st8*2)*1024 + r0;
        float4* op = (float4*)&out[ob];
        op[0] = make_float4(acc[0],  acc[1],  acc[2],  acc[3]);
        op[1] = make_float4(acc[4],  acc[5],  acc[6],  acc[7]);
        op[2] = make_float4(acc[8],  acc[9],  acc[10], acc[11]);
        op[3] = make_float4(acc[12], acc[13], acc[14], acc[15]);
        float4* op2 = (float4*)&out[ob + 1024];
        op2[0] = make_float4(acc[16], acc[17], acc[18], acc[19]);
        op2[1] = make_float4(acc[20], acc[21], acc[22], acc[23]);
        op2[2] = make_float4(acc[24], acc[25], acc[26], acc[27]);
        op2[3] = make_float4(acc[28], acc[29], acc[30], acc[31]);
        // no end-of-loop sync needed: next A writes y1l (readers done before B->C
        // sync); next B's y2l writes are fenced by next A's sync.
    }
}

extern "C" void kernel_launch(void* const* d_in, const int* in_sizes, int n_in,
                              void* d_out, int out_size, void* d_ws, size_t ws_size,
                              hipStream_t stream) {
    const float* x       = (const float*)d_in[0];
    const float* start_w = (const float*)d_in[1];
    const float* start_b = (const float*)d_in[2];
    const float* gt_w    = (const float*)d_in[3];
    const float* gt_b    = (const float*)d_in[4];
    const float* gs_w    = (const float*)d_in[5];
    const float* gs_b    = (const float*)d_in[6];
    const float* res_w   = (const float*)d_in[7];
    const float* res_b   = (const float*)d_in[8];
    const float* bn_g    = (const float*)d_in[9];
    const float* bn_b    = (const float*)d_in[10];
    const float* bn1_g   = (const float*)d_in[11];
    const float* bn1_b   = (const float*)d_in[12];
    const float* e1_w    = (const float*)d_in[13];
    const float* e1_b    = (const float*)d_in[14];
    const float* bn2_g   = (const float*)d_in[15];
    const float* bn2_b   = (const float*)d_in[16];
    const float* e2_w    = (const float*)d_in[17];
    const float* e2_b    = (const float*)d_in[18];
    float* ws  = (float*)d_ws;
    float* out = (float*)d_out;

    float* h    = ws + H_OFF;
    float* skip = ws + SK_OFF;
    float* st   = ws + ST_OFF;
    float* lst  = out;               // 20480 floats at head of d_out; dead before k_ep_c

    // feasibility of the cooperative path (host-side queries only; graph-safe)
    int coop_ok = 0;
    {
        int dev = 0, attr = 0, occ = 0;
        if (hipGetDevice(&dev) == hipSuccess &&
            hipDeviceGetAttribute(&attr, hipDeviceAttributeCooperativeLaunch, dev)
                == hipSuccess && attr) {
            if (hipOccupancyMaxActiveBlocksPerMultiprocessor(&occ, k_fused, 512, 0)
                    == hipSuccess && occ >= 2)
                coop_ok = 1;   // 512 blocks need >= 2 blocks/CU on 256 CUs
        }
    }

    k_zero<<<dim3(17), dim3(256), 0, stream>>>(st, ST_TOT);
    k_zero<<<dim3(80), dim3(256), 0, stream>>>(lst, LST_N);
    k_start<<<dim3(512), dim3(256), 0, stream>>>(x, start_w, start_b, h, skip);

    if (coop_ok) {
        void* kargs[12] = {
            (void*)&gt_w, (void*)&gt_b, (void*)&gs_w, (void*)&gs_b,
            (void*)&res_w, (void*)&res_b, (void*)&bn_g, (void*)&bn_b,
            (void*)&h, (void*)&skip, (void*)&st, (void*)&lst };
        if (hipLaunchCooperativeKernel(k_fused, dim3(512), dim3(512),
                                       kargs, 0, stream) != hipSuccess)
            coop_ok = 0;
    }
    if (!coop_ok) {
        // legacy per-layer path (round-0 verified)
        size_t need_full = ((size_t)ST_OFF + 8192 + 4*1024*1024) * 4;
        float* z = (ws_size >= need_full) ? (ws + ST_OFF + 8192)
                                          : (float*)d_out;
        for (int L = 0; L < 40; ++L)
            k_layer<<<dim3(1024), dim3(256), 0, stream>>>(
                gt_w, gt_b, gs_w, gs_b, res_w, res_b, bn_g, bn_b, h, z, skip, st, L);
    }

    k_ep_a<<<dim3(512), dim3(256), 0, stream>>>(skip, bn1_g, bn1_b, st);
    k_ep_b<<<dim3(1), dim3(256), 0, stream>>>(e1_w, e1_b, bn2_g, bn2_b, st);
    k_ep_c<<<dim3(1024), dim3(256), 0, stream>>>(skip, bn1_g, bn1_b, e1_w, e1_b,
                                                 e2_w, e2_b, st, out);
}

// Round 3
// 2595.131 us; speedup vs baseline: 1.0196x; 1.0061x over previous
//
#include <hip/hip_runtime.h>
#include <hip/hip_cooperative_groups.h>

namespace cg = cooperative_groups;

// WaveNet fused implementation, fp32.
// Layout trick: with dilation fixed at 1024, t = r + 1024*s decomposes the field
// into 8192 independent chains (b, r) of 16 steps x 32 channels.
// ws layout (floats): h [8192][32][16] @0, skip same @4M, stats @8M.
// Layer z-stats (8-way slot-replicated) live at the head of d_out (dead until k_ep_c).

#define EPSV 1e-5f
#define RN   (1.f/131072.f)

#define H_OFF  0
#define SK_OFF (4*1024*1024)
#define ST_OFF (8*1024*1024)
#define ST_SKIP 2560   // skip sum[32], sumsq[32]
#define ST_MU   2624   // y1 mean-sum [32]
#define ST_Y    2656   // y1 second-moment sums [32][32]
#define ST_A2   3680   // bn2 scale [256]
#define ST_B2   3936   // bn2 shift [256]
#define ST_TOT  4192
#define LST_N   (40*8*64)   // layer z-stats: [L][slot][sum32|sumsq32]

__device__ __forceinline__ float rcp_f(float x) { return __builtin_amdgcn_rcpf(x); }
__device__ __forceinline__ float tanh_f(float x) {
    float e = __expf(2.f * x);                 // inf for big x -> 1; 0 for very neg -> -1
    return 1.f - 2.f * rcp_f(e + 1.f);
}
__device__ __forceinline__ float sigm_f(float x) { return rcp_f(1.f + __expf(-x)); }
__device__ __forceinline__ float mish_f(float x) {
    float e = __expf(x);
    float sp = (x > 15.f) ? x : __logf(1.f + e);   // softplus, stable both tails
    return x * tanh_f(sp);
}

// ---------------- zero a region (ws / d_out are poisoned every launch) --------
__global__ void k_zero(float* __restrict__ p, int n) {
    int i = blockIdx.x * 256 + threadIdx.x;
    if (i < n) p[i] = 0.f;
}

// ---------------- start conv: h = W_s @ shift_right(x,1) + b_s ; skip = 0 -----
// block = 256 thr = 16 r' x 16 s positions; 512 blocks (b in blk>>6, r0=(blk&63)*16)
__global__ __launch_bounds__(256) void k_start(
        const float* __restrict__ x, const float* __restrict__ sw_g,
        const float* __restrict__ sb_g, float* __restrict__ h, float* __restrict__ skip)
{
    __shared__ float sw[256*36];   // W [c][o], row stride 36 (pad: bank rotate + 16B align)
    __shared__ float sb[32];
    int tid = threadIdx.x, blk = blockIdx.x;
    int b = blk >> 6, r0 = (blk & 63) << 4;
    for (int k = tid; k < 8192; k += 256) {        // sw_g is [o][c], k = o*256+c
        int o = k >> 8, c = k & 255;
        sw[c*36 + o] = sw_g[k];
    }
    if (tid < 32) sb[tid] = sb_g[tid];
    __syncthreads();

    int rr = tid & 15, s = tid >> 4;
    int t = r0 + rr + (s << 10);
    bool valid = (t >= 1);
    const float* xr = x + (long)b*256*16384 + (valid ? (t-1) : 0);
    float acc[32];
    #pragma unroll
    for (int o = 0; o < 32; ++o) acc[o] = 0.f;
    for (int c = 0; c < 256; ++c) {
        float xv = xr[(long)c*16384];
        xv = valid ? xv : 0.f;
        const float4* wrow = (const float4*)&sw[c*36];
        #pragma unroll
        for (int o4 = 0; o4 < 8; ++o4) {
            float4 w = wrow[o4];
            acc[o4*4+0] += w.x*xv; acc[o4*4+1] += w.y*xv;
            acc[o4*4+2] += w.z*xv; acc[o4*4+3] += w.w*xv;
        }
    }
    __syncthreads();                               // done reading sw; reuse as h stage
    #pragma unroll
    for (int o = 0; o < 32; ++o) sw[(rr*32 + o)*16 + s] = acc[o] + sb[o];
    __syncthreads();
    float4* hd = (float4*)(h + (long)blk*8192);
    float4* sd = (float4*)(skip + (long)blk*8192);
    const float4* ss = (const float4*)sw;
    float4 z4 = make_float4(0.f, 0.f, 0.f, 0.f);
    for (int k = tid; k < 2048; k += 256) { hd[k] = ss[k]; sd[k] = z4; }
}

// ------- helpers for the fused kernel: XOR-swizzled s_hg access ---------------
// s_hg chain region = 512 floats; channel i's 16 floats at i*16, but the q-th
// float4 slot is stored at (q ^ ((i>>1)&3)) -> staging writes go 16-way -> 4-way.
__device__ __forceinline__ void stage16(float* __restrict__ row, int o,
                                        const float* __restrict__ v) {
    float4* p = (float4*)row;
    int sw = (o >> 1) & 3;
    p[0^sw] = make_float4(v[0],  v[1],  v[2],  v[3]);
    p[1^sw] = make_float4(v[4],  v[5],  v[6],  v[7]);
    p[2^sw] = make_float4(v[8],  v[9],  v[10], v[11]);
    p[3^sw] = make_float4(v[12], v[13], v[14], v[15]);
}

__device__ __forceinline__ void gate_mv(const float* __restrict__ s_w,
        const float* __restrict__ hg, int o, float gtb, float gsb,
        float* __restrict__ aT, float* __restrict__ aS)
{
    #pragma unroll
    for (int s = 0; s < 16; ++s) { aT[s] = gtb; aS[s] = gsb; }
    #pragma unroll 4
    for (int i = 0; i < 32; ++i) {
        float4 w = *(const float4*)&s_w[(i*32 + o)*4];   // {wt0,wt1,ws0,ws1}
        const float4* hr = (const float4*)&hg[i*16];
        int swi = (i >> 1) & 3;
        float hv[16];
        *(float4*)&hv[0]  = hr[0^swi];
        *(float4*)&hv[4]  = hr[1^swi];
        *(float4*)&hv[8]  = hr[2^swi];
        *(float4*)&hv[12] = hr[3^swi];
        aT[0] += w.y*hv[0];  aS[0] += w.w*hv[0];          // s=0 shifted tap is 0
        #pragma unroll
        for (int s = 1; s < 16; ++s) {
            aT[s] += w.y*hv[s] + w.x*hv[s-1];
            aS[s] += w.w*hv[s] + w.z*hv[s-1];
        }
    }
}

__device__ __forceinline__ void res_mv(const float* __restrict__ s_r,
        const float* __restrict__ hg, int o, float rbv, float* __restrict__ zr)
{
    #pragma unroll
    for (int s = 0; s < 16; ++s) zr[s] = rbv;
    #pragma unroll 4
    for (int i = 0; i < 32; ++i) {
        float w = s_r[i*32 + o];
        const float4* gr = (const float4*)&hg[i*16];
        int swi = (i >> 1) & 3;
        float gv[16];
        *(float4*)&gv[0]  = gr[0^swi];
        *(float4*)&gv[4]  = gr[1^swi];
        *(float4*)&gv[8]  = gr[2^swi];
        *(float4*)&gv[12] = gr[3^swi];
        #pragma unroll
        for (int s = 0; s < 16; ++s) zr[s] += w*gv[s];
    }
}

// ---------------- fused 40-layer kernel (cooperative) -------------------------
// 512 blocks x 256 thr; each thread owns TWO chains (c0 and c0+8), channel o,
// 16 steps each. h / skip / z stay in VGPRs (96 persistent) across all 40 layers;
// the only cross-block dependency per layer is the z BN statistic:
// slot-replicated atomics + grid.sync(), read back with agent-scope coherent
// loads (lanes 0..31) and LDS-broadcast.
// LDS = 16384(s_w)+4096(s_r)+32768(s_hg)+1024(s_red)+256(s_ab) = 54528 B
//   -> 2 blocks/CU uses 109 KB of 160 KB (large slack vs alloc granularity).
// __launch_bounds__(256,2): VGPR cap 256 under BOTH readings of arg2 (2 waves/EU
// -> 512/2; or 2 blocks/CU = 8 waves/CU = 2/EU -> 512/2). Round-2's (512,4) was
// read as 4 blocks/CU -> cap 64 -> catastrophic scratch spills (695 MB HBM wr).
__global__ __launch_bounds__(256, 2) void k_fused2(
        const float* __restrict__ gt_w, const float* __restrict__ gt_b,
        const float* __restrict__ gs_w, const float* __restrict__ gs_b,
        const float* __restrict__ res_w, const float* __restrict__ res_b,
        const float* __restrict__ bn_g, const float* __restrict__ bn_b,
        const float* __restrict__ h, float* __restrict__ skip,
        float* __restrict__ st, float* __restrict__ lst)
{
    __shared__ float s_w[4096];      // [i][o][4] = {wt0, wt1, ws0, ws1}
    __shared__ float s_r[1024];      // [i][o]
    __shared__ float s_hg[8192];     // per-chain h then g, [chl][512], 16 chains
    __shared__ float s_red[4][32][2];
    __shared__ float s_ab[64];       // bn affine broadcast: a[32], b[32]

    int tid = threadIdx.x;
    int o = tid & 31, c0 = tid >> 5;           // chains c0 and c0+8
    long baseA = (long)blockIdx.x*8192 + c0*512 + o*16;
    long baseB = baseA + 8*512;
    int slot = blockIdx.x & 7;
    float* rowA = &s_hg[c0*512 + o*16];
    float* rowB = &s_hg[(c0+8)*512 + o*16];

    float hA[16], hB[16], skA[16], skB[16], zrA[16], zrB[16];
    {
        const float4* pa = (const float4*)(h + baseA);
        const float4* pb = (const float4*)(h + baseB);
        #pragma unroll
        for (int q = 0; q < 4; ++q) {
            float4 ta = pa[q], tb = pb[q];
            hA[4*q+0]=ta.x; hA[4*q+1]=ta.y; hA[4*q+2]=ta.z; hA[4*q+3]=ta.w;
            hB[4*q+0]=tb.x; hB[4*q+1]=tb.y; hB[4*q+2]=tb.z; hB[4*q+3]=tb.w;
        }
    }
    #pragma unroll
    for (int s = 0; s < 16; ++s) { skA[s] = 0.f; skB[s] = 0.f; }

    cg::grid_group grid = cg::this_grid();

    for (int L = 0; L < 40; ++L) {
        // stage weights: gt_w/gs_w are [L][o][i][2], res_w is [L][o][i]
        for (int k = tid; k < 1024; k += 256) {
            int oo = k >> 5, ii = k & 31;
            float2 a = ((const float2*)(gt_w + (long)L*2048))[k];
            float2 c = ((const float2*)(gs_w + (long)L*2048))[k];
            float* d = &s_w[(ii*32 + oo)*4];
            d[0] = a.x; d[1] = a.y; d[2] = c.x; d[3] = c.y;
            s_r[ii*32 + oo] = res_w[(long)L*1024 + k];
        }
        if (L > 0 && tid < 32) {     // bn stats of layer L-1 (synced last iter)
            float ssum = 0.f, ssq = 0.f;
            #pragma unroll
            for (int r = 0; r < 8; ++r) {
                ssum += __hip_atomic_load(&lst[((L-1)*8 + r)*64 + tid],
                                          __ATOMIC_RELAXED, __HIP_MEMORY_SCOPE_AGENT);
                ssq  += __hip_atomic_load(&lst[((L-1)*8 + r)*64 + 32 + tid],
                                          __ATOMIC_RELAXED, __HIP_MEMORY_SCOPE_AGENT);
            }
            float m = ssum * RN;
            float v = ssq * RN - m*m;
            float a = rsqrtf(v + EPSV) * bn_g[(L-1)*32 + tid];
            s_ab[tid] = a;
            s_ab[32 + tid] = bn_b[(L-1)*32 + tid] - m*a;
        }
        __syncthreads();             // s_w/s_r/s_ab staged

        if (L > 0) {                 // h += bn(z) residual
            float a = s_ab[o], bb = s_ab[32 + o];
            #pragma unroll
            for (int s = 0; s < 16; ++s) {
                hA[s] += zrA[s]*a + bb;
                hB[s] += zrB[s]*a + bb;
            }
        }

        // stage h (s_hg traffic is produced+consumed within the half-wave; DS ops
        // are wave-ordered, so no block barrier is needed around s_hg)
        stage16(rowA, o, hA);
        stage16(rowB, o, hB);

        float gA[16], gB[16];
        {
            float aT[16], aS[16];
            float gtb = gt_b[L*32 + o], gsb = gs_b[L*32 + o];
            gate_mv(s_w, &s_hg[c0*512], o, gtb, gsb, aT, aS);
            #pragma unroll
            for (int s = 0; s < 16; ++s) {
                gA[s] = tanh_f(aT[s]) * sigm_f(aS[s]);
                skA[s] += gA[s];
            }
            gate_mv(s_w, &s_hg[(c0+8)*512], o, gtb, gsb, aT, aS);
            #pragma unroll
            for (int s = 0; s < 16; ++s) {
                gB[s] = tanh_f(aT[s]) * sigm_f(aS[s]);
                skB[s] += gB[s];
            }
        }

        if (L < 39) {     // layer 39's z / bn stats are dead
            stage16(rowA, o, gA);
            stage16(rowB, o, gB);
            float rbv = res_b[L*32 + o];
            res_mv(s_r, &s_hg[c0*512],     o, rbv, zrA);
            res_mv(s_r, &s_hg[(c0+8)*512], o, rbv, zrB);

            // z stats: per-thread (both chains) -> half-wave merge -> LDS -> atomics
            float ps = 0.f, pq = 0.f;
            #pragma unroll
            for (int s = 0; s < 16; ++s) {
                ps += zrA[s] + zrB[s];
                pq += zrA[s]*zrA[s] + zrB[s]*zrB[s];
            }
            ps += __shfl_down(ps, 32); pq += __shfl_down(pq, 32);
            int wv = tid >> 6;
            if ((tid & 63) < 32) { s_red[wv][o][0] = ps; s_red[wv][o][1] = pq; }
            __syncthreads();
            if (tid < 32) {
                float a = s_red[0][tid][0] + s_red[1][tid][0]
                        + s_red[2][tid][0] + s_red[3][tid][0];
                atomicAdd(&lst[(L*8 + slot)*64 + tid], a);
            } else if (tid < 64) {
                int c = tid - 32;
                float a = s_red[0][c][1] + s_red[1][c][1]
                        + s_red[2][c][1] + s_red[3][c][1];
                atomicAdd(&lst[(L*8 + slot)*64 + 32 + c], a);
            }
            grid.sync();   // stats of layer L complete + visible before layer L+1
        }
    }

    // final skip write + fold skip-stat pass (values still in regs)
    {
        float4* pa = (float4*)(skip + baseA);
        float4* pb = (float4*)(skip + baseB);
        #pragma unroll
        for (int q = 0; q < 4; ++q) {
            pa[q] = make_float4(skA[4*q], skA[4*q+1], skA[4*q+2], skA[4*q+3]);
            pb[q] = make_float4(skB[4*q], skB[4*q+1], skB[4*q+2], skB[4*q+3]);
        }
        float p2 = 0.f, q2 = 0.f;
        #pragma unroll
        for (int s = 0; s < 16; ++s) {
            p2 += skA[s] + skB[s];
            q2 += skA[s]*skA[s] + skB[s]*skB[s];
        }
        p2 += __shfl_down(p2, 32); q2 += __shfl_down(q2, 32);
        int wv = tid >> 6;
        if ((tid & 63) < 32) { s_red[wv][o][0] = p2; s_red[wv][o][1] = q2; }
        __syncthreads();
        if (tid < 32) {
            float a = s_red[0][tid][0] + s_red[1][tid][0]
                    + s_red[2][tid][0] + s_red[3][tid][0];
            atomicAdd(&st[ST_SKIP + tid], a);
        } else if (tid < 64) {
            int c = tid - 32;
            float a = s_red[0][c][1] + s_red[1][c][1]
                    + s_red[2][c][1] + s_red[3][c][1];
            atomicAdd(&st[ST_SKIP + 32 + c], a);
        }
    }
}

// ---------------- legacy per-layer kernel (fallback if coop launch refused) ---
__global__ __launch_bounds__(256) void k_layer(
        const float* __restrict__ gt_w, const float* __restrict__ gt_b,
        const float* __restrict__ gs_w, const float* __restrict__ gs_b,
        const float* __restrict__ res_w, const float* __restrict__ res_b,
        const float* __restrict__ bn_g, const float* __restrict__ bn_b,
        float* __restrict__ h, float* __restrict__ z, float* __restrict__ skip,
        float* __restrict__ st, int L)
{
    __shared__ float s_w[4096];
    __shared__ float s_r[1024];
    __shared__ float s_hg[4096];
    __shared__ float s_red[4][32][2];

    int tid = threadIdx.x;
    int o = tid & 31, chl = tid >> 5;
    long base = (long)blockIdx.x*4096 + chl*512 + o*16;

    for (int k = tid; k < 1024; k += 256) {
        int oo = k >> 5, ii = k & 31;
        float2 a = ((const float2*)(gt_w + (long)L*2048))[k];
        float2 c = ((const float2*)(gs_w + (long)L*2048))[k];
        float* d = &s_w[(ii*32 + oo)*4];
        d[0] = a.x; d[1] = a.y; d[2] = c.x; d[3] = c.y;
        s_r[ii*32 + oo] = res_w[(long)L*1024 + k];
    }

    float hreg[16];
    float4* hp4 = (float4*)(h + base);
    #pragma unroll
    for (int q = 0; q < 4; ++q) {
        float4 t4 = hp4[q];
        hreg[4*q+0]=t4.x; hreg[4*q+1]=t4.y; hreg[4*q+2]=t4.z; hreg[4*q+3]=t4.w;
    }
    if (L > 0) {
        float ssum = st[(L-1)*64 + o], ssq = st[(L-1)*64 + 32 + o];
        float m = ssum * RN;
        float v = ssq * RN - m*m;
        float a = rsqrtf(v + EPSV) * bn_g[(L-1)*32 + o];
        float bb = bn_b[(L-1)*32 + o] - m*a;
        const float4* zp4 = (const float4*)(z + base);
        #pragma unroll
        for (int q = 0; q < 4; ++q) {
            float4 t4 = zp4[q];
            hreg[4*q+0] += t4.x*a + bb; hreg[4*q+1] += t4.y*a + bb;
            hreg[4*q+2] += t4.z*a + bb; hreg[4*q+3] += t4.w*a + bb;
        }
        #pragma unroll
        for (int q = 0; q < 4; ++q)
            hp4[q] = make_float4(hreg[4*q], hreg[4*q+1], hreg[4*q+2], hreg[4*q+3]);
    }
    float4* hs4 = (float4*)&s_hg[chl*512 + o*16];
    #pragma unroll
    for (int q = 0; q < 4; ++q)
        hs4[q] = make_float4(hreg[4*q], hreg[4*q+1], hreg[4*q+2], hreg[4*q+3]);
    __syncthreads();

    float aT[16], aS[16];
    float gtb = gt_b[L*32 + o], gsb = gs_b[L*32 + o];
    #pragma unroll
    for (int s = 0; s < 16; ++s) { aT[s] = gtb; aS[s] = gsb; }
    #pragma unroll 4
    for (int i = 0; i < 32; ++i) {
        float4 w = *(const float4*)&s_w[(i*32 + o)*4];
        const float4* hr = (const float4*)&s_hg[chl*512 + i*16];
        float hp = 0.f;
        #pragma unroll
        for (int s4 = 0; s4 < 4; ++s4) {
            float4 hv = hr[s4];
            int s = 4*s4;
            aT[s+0] += w.y*hv.x + w.x*hp;   aS[s+0] += w.w*hv.x + w.z*hp;
            aT[s+1] += w.y*hv.y + w.x*hv.x; aS[s+1] += w.w*hv.y + w.z*hv.x;
            aT[s+2] += w.y*hv.z + w.x*hv.y; aS[s+2] += w.w*hv.z + w.z*hv.y;
            aT[s+3] += w.y*hv.w + w.x*hv.z; aS[s+3] += w.w*hv.w + w.z*hv.z;
            hp = hv.w;
        }
    }
    float g[16], sk[16];
    #pragma unroll
    for (int s = 0; s < 16; ++s) g[s] = tanh_f(aT[s]) * sigm_f(aS[s]);

    float4* skp4 = (float4*)(skip + base);
    #pragma unroll
    for (int q = 0; q < 4; ++q) {
        float4 t4 = skp4[q];
        sk[4*q+0] = t4.x + g[4*q+0]; sk[4*q+1] = t4.y + g[4*q+1];
        sk[4*q+2] = t4.z + g[4*q+2]; sk[4*q+3] = t4.w + g[4*q+3];
        skp4[q] = make_float4(sk[4*q], sk[4*q+1], sk[4*q+2], sk[4*q+3]);
    }

    __syncthreads();
    #pragma unroll
    for (int q = 0; q < 4; ++q)
        hs4[q] = make_float4(g[4*q], g[4*q+1], g[4*q+2], g[4*q+3]);
    __syncthreads();

    float az[16];
    float rbv = res_b[L*32 + o];
    #pragma unroll
    for (int s = 0; s < 16; ++s) az[s] = rbv;
    #pragma unroll 4
    for (int i = 0; i < 32; ++i) {
        float w = s_r[i*32 + o];
        const float4* gr = (const float4*)&s_hg[chl*512 + i*16];
        #pragma unroll
        for (int s4 = 0; s4 < 4; ++s4) {
            float4 gv = gr[s4];
            az[4*s4+0] += w*gv.x; az[4*s4+1] += w*gv.y;
            az[4*s4+2] += w*gv.z; az[4*s4+3] += w*gv.w;
        }
    }
    float4* zp4w = (float4*)(z + base);
    #pragma unroll
    for (int q = 0; q < 4; ++q)
        zp4w[q] = make_float4(az[4*q], az[4*q+1], az[4*q+2], az[4*q+3]);

    float ps = 0.f, pq = 0.f;
    #pragma unroll
    for (int s = 0; s < 16; ++s) { ps += az[s]; pq += az[s]*az[s]; }
    ps += __shfl_down(ps, 32); pq += __shfl_down(pq, 32);
    int wv = tid >> 6;
    if ((tid & 63) < 32) { s_red[wv][o][0] = ps; s_red[wv][o][1] = pq; }
    __syncthreads();
    if (tid < 32) {
        float a = s_red[0][tid][0] + s_red[1][tid][0] + s_red[2][tid][0] + s_red[3][tid][0];
        atomicAdd(&st[L*64 + tid], a);
    } else if (tid < 64) {
        int c = tid - 32;
        float a = s_red[0][c][1] + s_red[1][c][1] + s_red[2][c][1] + s_red[3][c][1];
        atomicAdd(&st[L*64 + 32 + c], a);
    }

    if (L == 39) {
        float p2 = 0.f, q2 = 0.f;
        #pragma unroll
        for (int s = 0; s < 16; ++s) { p2 += sk[s]; q2 += sk[s]*sk[s]; }
        p2 += __shfl_down(p2, 32); q2 += __shfl_down(q2, 32);
        __syncthreads();
        if ((tid & 63) < 32) { s_red[wv][o][0] = p2; s_red[wv][o][1] = q2; }
        __syncthreads();
        if (tid < 32) {
            float a = s_red[0][tid][0] + s_red[1][tid][0] + s_red[2][tid][0] + s_red[3][tid][0];
            atomicAdd(&st[ST_SKIP + tid], a);
        } else if (tid < 64) {
            int c = tid - 32;
            float a = s_red[0][c][1] + s_red[1][c][1] + s_red[2][c][1] + s_red[3][c][1];
            atomicAdd(&st[ST_SKIP + 32 + c], a);
        }
    }
}

// ---------------- epilogue A: y1 = mish(bn1(skip)); accumulate mean + 2nd moments
__global__ __launch_bounds__(256) void k_ep_a(
        const float* __restrict__ skip, const float* __restrict__ bn1_g,
        const float* __restrict__ bn1_b, float* __restrict__ st)
{
    __shared__ float sy[256*33];     // y1 [p][i], stride 33
    __shared__ float sA[32], sB[32];
    int tid = threadIdx.x;
    long cb = (long)blockIdx.x * 8192;
    if (tid < 32) {
        float ssum = st[ST_SKIP + tid], ssq = st[ST_SKIP + 32 + tid];
        float m = ssum * RN, v = ssq * RN - m*m;
        float a = rsqrtf(v + EPSV) * bn1_g[tid];
        sA[tid] = a; sB[tid] = bn1_b[tid] - m*a;
    }
    __syncthreads();
    for (int k = tid; k < 8192; k += 256) {
        int i = k & 31, p = k >> 5;
        int rr = p & 15, s = p >> 4;
        float v = skip[cb + rr*512 + i*16 + s];
        sy[p*33 + i] = mish_f(v * sA[i] + sB[i]);
    }
    __syncthreads();
    if (tid < 32) {
        float mu = 0.f;
        for (int p = 0; p < 256; ++p) mu += sy[p*33 + tid];
        atomicAdd(&st[ST_MU + tid], mu);
    }
    int jj = tid & 31, i0 = tid >> 5;    // 8 x 32 -> 4 (i,j) pairs per thread
    float a0 = 0.f, a1 = 0.f, a2 = 0.f, a3 = 0.f;
    for (int p = 0; p < 256; ++p) {
        float yj = sy[p*33 + jj];
        a0 += yj * sy[p*33 + i0];
        a1 += yj * sy[p*33 + i0 + 8];
        a2 += yj * sy[p*33 + i0 + 16];
        a3 += yj * sy[p*33 + i0 + 24];
    }
    atomicAdd(&st[ST_Y + (i0     )*32 + jj], a0);
    atomicAdd(&st[ST_Y + (i0 +  8)*32 + jj], a1);
    atomicAdd(&st[ST_Y + (i0 + 16)*32 + jj], a2);
    atomicAdd(&st[ST_Y + (i0 + 24)*32 + jj], a3);
}

// ---------------- epilogue B: analytic bn2 stats: var(e1_w@y1) = w^T Cov(y1) w --
__global__ void k_ep_b(
        const float* __restrict__ e1_w, const float* __restrict__ e1_b,
        const float* __restrict__ bn2_g, const float* __restrict__ bn2_b,
        float* __restrict__ st)
{
    __shared__ float mu[32];
    int o = threadIdx.x;
    if (o < 32) mu[o] = st[ST_MU + o] * RN;
    __syncthreads();
    float w[32];
    const float4* wr = (const float4*)(e1_w + o*32);
    #pragma unroll
    for (int q = 0; q < 8; ++q) {
        float4 t4 = wr[q];
        w[4*q]=t4.x; w[4*q+1]=t4.y; w[4*q+2]=t4.z; w[4*q+3]=t4.w;
    }
    float m2 = e1_b[o];
    #pragma unroll
    for (int i = 0; i < 32; ++i) m2 += w[i]*mu[i];
    float var = 0.f;
    for (int i = 0; i < 32; ++i) {
        float wi = w[i], mi = mu[i];
        for (int j = 0; j < 32; ++j)
            var += wi * w[j] * (st[ST_Y + i*32 + j]*RN - mi*mu[j]);
    }
    float a2 = rsqrtf(var + EPSV) * bn2_g[o];
    st[ST_A2 + o] = a2;
    st[ST_B2 + o] = bn2_b[o] - m2*a2;
}

// ---------------- epilogue C: out = e2 @ mish(bn2(e1 @ mish(bn1(skip)))) + b ----
// block = 256 thr (thread = output/e-channel), tile = 16 chains; 4 subtiles of
// 32 pos per block, 1024 blocks. LDS trimmed to exactly 40960 B -> 4 blocks/CU.
__global__ __launch_bounds__(256, 4) void k_ep_c(
        const float* __restrict__ skip,
        const float* __restrict__ bn1_g, const float* __restrict__ bn1_b,
        const float* __restrict__ e1_w, const float* __restrict__ e1_b,
        const float* __restrict__ e2_w, const float* __restrict__ e2_b,
        const float* __restrict__ st, float* __restrict__ out)
{
    __shared__ float y1l[32*32];     // [i][q]
    __shared__ float y2l[256*36];    // [i][q], stride 36 (bank rotate, 16B aligned)
    int tid = threadIdx.x;
    int blk2 = blockIdx.x;
    int blk = blk2 >> 1, half = blk2 & 1;
    int b = blk >> 6, r0 = (blk & 63) << 4;
    long cb = (long)blk * 8192;
    float w1[32];
    {
        const float4* wr = (const float4*)(e1_w + tid*32);
        #pragma unroll
        for (int q = 0; q < 8; ++q) {
            float4 t4 = wr[q];
            w1[4*q]=t4.x; w1[4*q+1]=t4.y; w1[4*q+2]=t4.z; w1[4*q+3]=t4.w;
        }
    }
    float a2 = st[ST_A2 + tid], b2 = st[ST_B2 + tid];
    float eb1 = e1_b[tid];
    float eb2 = e2_b[tid];
    const float4* w2row = (const float4*)(e2_w + (long)tid * 256);

    for (int st8 = half*4; st8 < half*4 + 4; ++st8) {   // q = sl*16+rr, s = st8*2+sl
        for (int k = tid; k < 1024; k += 256) {  // phase A: y1 (32 i x 32 q)
            int i = k >> 5, q = k & 31;
            float ssum = st[ST_SKIP + i], ssq = st[ST_SKIP + 32 + i];
            float m = ssum * RN, vv = ssq * RN - m*m;
            float a1 = rsqrtf(vv + EPSV) * bn1_g[i];
            float b1 = bn1_b[i] - m*a1;
            int rr = q & 15, sl = q >> 4;
            float v = skip[cb + rr*512 + i*16 + st8*2 + sl];
            y1l[i*32 + q] = mish_f(v * a1 + b1);
        }
        __syncthreads();
        // phase B: z2 = e1@y1 (thread = channel), y2 = mish(bn2(z2)) -> LDS
        #pragma unroll 2
        for (int q4 = 0; q4 < 8; ++q4) {
            float4 acc = make_float4(eb1, eb1, eb1, eb1);
            #pragma unroll 8
            for (int i = 0; i < 32; ++i) {
                float4 yv = *(const float4*)&y1l[i*32 + q4*4];
                float wi = w1[i];
                acc.x += wi*yv.x; acc.y += wi*yv.y; acc.z += wi*yv.z; acc.w += wi*yv.w;
            }
            float4 y2v;
            y2v.x = mish_f(acc.x*a2 + b2);
            y2v.y = mish_f(acc.y*a2 + b2);
            y2v.z = mish_f(acc.z*a2 + b2);
            y2v.w = mish_f(acc.w*a2 + b2);
            *(float4*)&y2l[tid*36 + q4*4] = y2v;
        }
        __syncthreads();
        // phase C: out row = e2_w[tid,:] @ y2 (the big GEMM)
        float acc[32];
        #pragma unroll
        for (int q = 0; q < 32; ++q) acc[q] = eb2;
        for (int i4 = 0; i4 < 64; ++i4) {
            float4 w4 = w2row[i4];
            float wa[4] = {w4.x, w4.y, w4.z, w4.w};
            #pragma unroll
            for (int ii = 0; ii < 4; ++ii) {
                float wv = wa[ii];
                const float* yr = &y2l[(i4*4 + ii)*36];
                #pragma unroll
                for (int q4 = 0; q4 < 8; ++q4) {
                    float4 yv = *(const float4*)&yr[q4*4];
                    acc[q4*4+0] += wv*yv.x; acc[q4*4+1] += wv*yv.y;
                    acc[q4*4+2] += wv*yv.z; acc[q4*4+3] += wv*yv.w;
                }
            }
        }
        long ob = ((long)b*256 + tid)*16384 + (long)(st8*2)*1024 + r0;
        float4* op = (float4*)&out[ob];
        op[0] = make_float4(acc[0],  acc[1],  acc[2],  acc[3]);
        op[1] = make_float4(acc[4],  acc[5],  acc[6],  acc[7]);
        op[2] = make_float4(acc[8],  acc[9],  acc[10], acc[11]);
        op[3] = make_float4(acc[12], acc[13], acc[14], acc[15]);
        float4* op2 = (float4*)&out[ob + 1024];
        op2[0] = make_float4(acc[16], acc[17], acc[18], acc[19]);
        op2[1] = make_float4(acc[20], acc[21], acc[22], acc[23]);
        op2[2] = make_float4(acc[24], acc[25], acc[26], acc[27]);
        op2[3] = make_float4(acc[28], acc[29], acc[30], acc[31]);
        // no end-of-loop sync needed: next A writes y1l (readers done before B->C
        // sync); next B's y2l writes are fenced by next A's sync.
    }
}

extern "C" void kernel_launch(void* const* d_in, const int* in_sizes, int n_in,
                              void* d_out, int out_size, void* d_ws, size_t ws_size,
                              hipStream_t stream) {
    const float* x       = (const float*)d_in[0];
    const float* start_w = (const float*)d_in[1];
    const float* start_b = (const float*)d_in[2];
    const float* gt_w    = (const float*)d_in[3];
    const float* gt_b    = (const float*)d_in[4];
    const float* gs_w    = (const float*)d_in[5];
    const float* gs_b    = (const float*)d_in[6];
    const float* res_w   = (const float*)d_in[7];
    const float* res_b   = (const float*)d_in[8];
    const float* bn_g    = (const float*)d_in[9];
    const float* bn_b    = (const float*)d_in[10];
    const float* bn1_g   = (const float*)d_in[11];
    const float* bn1_b   = (const float*)d_in[12];
    const float* e1_w    = (const float*)d_in[13];
    const float* e1_b    = (const float*)d_in[14];
    const float* bn2_g   = (const float*)d_in[15];
    const float* bn2_b   = (const float*)d_in[16];
    const float* e2_w    = (const float*)d_in[17];
    const float* e2_b    = (const float*)d_in[18];
    float* ws  = (float*)d_ws;
    float* out = (float*)d_out;

    float* h    = ws + H_OFF;
    float* skip = ws + SK_OFF;
    float* st   = ws + ST_OFF;
    float* lst  = out;               // 20480 floats at head of d_out; dead before k_ep_c

    // feasibility of the cooperative path (host-side queries only; graph-safe)
    int coop_ok = 0;
    {
        int dev = 0, attr = 0, occ = 0;
        if (hipGetDevice(&dev) == hipSuccess &&
            hipDeviceGetAttribute(&attr, hipDeviceAttributeCooperativeLaunch, dev)
                == hipSuccess && attr) {
            if (hipOccupancyMaxActiveBlocksPerMultiprocessor(&occ, k_fused2, 256, 0)
                    == hipSuccess && occ >= 2)
                coop_ok = 1;   // 512 blocks need >= 2 blocks/CU on 256 CUs
        }
    }

    k_zero<<<dim3(17), dim3(256), 0, stream>>>(st, ST_TOT);
    k_zero<<<dim3(80), dim3(256), 0, stream>>>(lst, LST_N);
    k_start<<<dim3(512), dim3(256), 0, stream>>>(x, start_w, start_b, h, skip);

    if (coop_ok) {
        void* kargs[12] = {
            (void*)&gt_w, (void*)&gt_b, (void*)&gs_w, (void*)&gs_b,
            (void*)&res_w, (void*)&res_b, (void*)&bn_g, (void*)&bn_b,
            (void*)&h, (void*)&skip, (void*)&st, (void*)&lst };
        if (hipLaunchCooperativeKernel(k_fused2, dim3(512), dim3(256),
                                       kargs, 0, stream) != hipSuccess)
            coop_ok = 0;
    }
    if (!coop_ok) {
        // legacy per-layer path (round-0 verified)
        size_t need_full = ((size_t)ST_OFF + 8192 + 4*1024*1024) * 4;
        float* z = (ws_size >= need_full) ? (ws + ST_OFF + 8192)
                                          : (float*)d_out;
        for (int L = 0; L < 40; ++L)
            k_layer<<<dim3(1024), dim3(256), 0, stream>>>(
                gt_w, gt_b, gs_w, gs_b, res_w, res_b, bn_g, bn_b, h, z, skip, st, L);
    }

    k_ep_a<<<dim3(512), dim3(256), 0, stream>>>(skip, bn1_g, bn1_b, st);
    k_ep_b<<<dim3(1), dim3(256), 0, stream>>>(e1_w, e1_b, bn2_g, bn2_b, st);
    k_ep_c<<<dim3(1024), dim3(256), 0, stream>>>(skip, bn1_g, bn1_b, e1_w, e1_b,
                                                 e2_w, e2_b, st, out);
}